// Round 1
// baseline (496.823 us; speedup 1.0000x reference)
//
#include <hip/hip_runtime.h>
#include <math.h>

#define ROWS 8
#define TPB 256
#define NNEG 2048
#define D 128

// ---------------- prep: normalize negatives (transposed) + log(samp_p) ----------------
__global__ __launch_bounds__(TPB) void sspe_prep(
    const float* __restrict__ embed,
    const float* __restrict__ sprobs,
    const int* __restrict__ sidx,
    float* __restrict__ en_t,      // [D][NNEG]
    float* __restrict__ ln_samp)   // [NNEG]
{
    const int t = threadIdx.x;
    const int wave = t >> 6;
    const int lane = t & 63;
    const int j = blockIdx.x * 4 + wave;   // one wave per negative row
    const int idx = sidx[j];

    float2 v = reinterpret_cast<const float2*>(embed)[(size_t)idx * 64 + lane];
    float ss = v.x * v.x + v.y * v.y;
    ss += __shfl_xor(ss, 1);
    ss += __shfl_xor(ss, 2);
    ss += __shfl_xor(ss, 4);
    ss += __shfl_xor(ss, 8);
    ss += __shfl_xor(ss, 16);
    ss += __shfl_xor(ss, 32);
    const float rinv = 1.0f / fmaxf(sqrtf(ss), 1e-12f);
    en_t[(size_t)(lane * 2) * NNEG + j]     = v.x * rinv;
    en_t[(size_t)(lane * 2 + 1) * NNEG + j] = v.y * rinv;
    if (lane == 0) ln_samp[j] = logf(sprobs[idx] + 1e-10f);
}

// ---------------- main: fused normalize + pos logit + GEMM + logsumexp ----------------
__global__ __launch_bounds__(TPB) void sspe_main(
    const float* __restrict__ hidden,
    const int* __restrict__ y,
    const float* __restrict__ embed,
    const float* __restrict__ sprobs,
    const int* __restrict__ sidx,
    const float* __restrict__ ltemp,
    const float* __restrict__ en_t,
    const float* __restrict__ ln_samp,
    float2* __restrict__ partials)
{
    const int t = threadIdx.x;
    const int wave = t >> 6;
    const int lane = t & 63;
    const int rb = blockIdx.x * ROWS;

    __shared__ __align__(16) float hs[ROWS][D];
    __shared__ float pos_adj_s[ROWS];
    __shared__ int   yf_s[ROWS];
    __shared__ float red[ROWS][4];
    __shared__ float rowmax[ROWS];

    const float temp = expf(fminf(ltemp[0], 4.6f));

    if (t < ROWS) yf_s[t] = y[rb + t];

    // Phase A: load + L2-normalize 8 hidden rows into LDS
    {
        const int r  = t >> 5;
        const int c4 = t & 31;
        float4 v = reinterpret_cast<const float4*>(hidden)[(size_t)(rb + r) * 32 + c4];
        float ss = v.x * v.x + v.y * v.y + v.z * v.z + v.w * v.w;
        ss += __shfl_xor(ss, 1);
        ss += __shfl_xor(ss, 2);
        ss += __shfl_xor(ss, 4);
        ss += __shfl_xor(ss, 8);
        ss += __shfl_xor(ss, 16);
        const float rinv = 1.0f / fmaxf(sqrtf(ss), 1e-12f);
        v.x *= rinv; v.y *= rinv; v.z *= rinv; v.w *= rinv;
        reinterpret_cast<float4*>(&hs[r][0])[c4] = v;
    }
    __syncthreads();

    // Phase B: positive logits. Wave w handles rows 2w + (lane>>5).
    {
        const int pr = 2 * wave + (lane >> 5);
        const int pc = lane & 31;
        const int yi = yf_s[pr];
        float4 e  = reinterpret_cast<const float4*>(embed)[(size_t)yi * 32 + pc];
        float4 hn = reinterpret_cast<const float4*>(&hs[pr][0])[pc];
        float ess = e.x * e.x + e.y * e.y + e.z * e.z + e.w * e.w;
        float dt  = e.x * hn.x + e.y * hn.y + e.z * hn.z + e.w * hn.w;
        ess += __shfl_xor(ess, 1);  dt += __shfl_xor(dt, 1);
        ess += __shfl_xor(ess, 2);  dt += __shfl_xor(dt, 2);
        ess += __shfl_xor(ess, 4);  dt += __shfl_xor(dt, 4);
        ess += __shfl_xor(ess, 8);  dt += __shfl_xor(dt, 8);
        ess += __shfl_xor(ess, 16); dt += __shfl_xor(dt, 16);
        if (pc == 0) {
            const float pl = dt * (1.0f / fmaxf(sqrtf(ess), 1e-12f)) * temp;
            pos_adj_s[pr] = pl - logf(sprobs[yi] + 1e-10f);
        }
    }

    // Phase C: 8-row x 8-neg register-tiled fp32 GEMM against en_t [D][NNEG]
    float acc[ROWS][8];
    #pragma unroll
    for (int r = 0; r < ROWS; ++r)
        #pragma unroll
        for (int k = 0; k < 8; ++k) acc[r][k] = 0.0f;

    const float4* en4 = reinterpret_cast<const float4*>(en_t) + 2 * t;
    for (int d4 = 0; d4 < 32; ++d4) {
        float4 hv[ROWS];
        #pragma unroll
        for (int r = 0; r < ROWS; ++r)
            hv[r] = reinterpret_cast<const float4*>(&hs[r][0])[d4];
        #pragma unroll
        for (int q = 0; q < 4; ++q) {
            const float4 a = en4[(size_t)(d4 * 4 + q) * (NNEG / 4)];
            const float4 b = en4[(size_t)(d4 * 4 + q) * (NNEG / 4) + 1];
            #pragma unroll
            for (int r = 0; r < ROWS; ++r) {
                const float h = (q == 0) ? hv[r].x : (q == 1) ? hv[r].y
                              : (q == 2) ? hv[r].z : hv[r].w;
                acc[r][0] = fmaf(h, a.x, acc[r][0]);
                acc[r][1] = fmaf(h, a.y, acc[r][1]);
                acc[r][2] = fmaf(h, a.z, acc[r][2]);
                acc[r][3] = fmaf(h, a.w, acc[r][3]);
                acc[r][4] = fmaf(h, b.x, acc[r][4]);
                acc[r][5] = fmaf(h, b.y, acc[r][5]);
                acc[r][6] = fmaf(h, b.z, acc[r][6]);
                acc[r][7] = fmaf(h, b.w, acc[r][7]);
            }
        }
    }

    // Phase D: mask collisions, adjust, per-row logsumexp
    int   idxk[8];
    float lnk[8];
    {
        const int4 i0 = reinterpret_cast<const int4*>(sidx)[2 * t];
        const int4 i1 = reinterpret_cast<const int4*>(sidx)[2 * t + 1];
        idxk[0] = i0.x; idxk[1] = i0.y; idxk[2] = i0.z; idxk[3] = i0.w;
        idxk[4] = i1.x; idxk[5] = i1.y; idxk[6] = i1.z; idxk[7] = i1.w;
        const float4 l0 = reinterpret_cast<const float4*>(ln_samp)[2 * t];
        const float4 l1 = reinterpret_cast<const float4*>(ln_samp)[2 * t + 1];
        lnk[0] = l0.x; lnk[1] = l0.y; lnk[2] = l0.z; lnk[3] = l0.w;
        lnk[4] = l1.x; lnk[5] = l1.y; lnk[6] = l1.z; lnk[7] = l1.w;
    }

    #pragma unroll
    for (int r = 0; r < ROWS; ++r) {
        const int yr = yf_s[r];
        float lm = -3e38f;
        #pragma unroll
        for (int k = 0; k < 8; ++k) {
            float lg = acc[r][k] * temp - lnk[k];
            if (idxk[k] == yr) lg = -3e38f;
            acc[r][k] = lg;
            lm = fmaxf(lm, lg);
        }
        lm = fmaxf(lm, __shfl_xor(lm, 1));
        lm = fmaxf(lm, __shfl_xor(lm, 2));
        lm = fmaxf(lm, __shfl_xor(lm, 4));
        lm = fmaxf(lm, __shfl_xor(lm, 8));
        lm = fmaxf(lm, __shfl_xor(lm, 16));
        lm = fmaxf(lm, __shfl_xor(lm, 32));
        if (lane == 0) red[r][wave] = lm;
    }
    __syncthreads();
    if (t < ROWS) {
        const float m = fmaxf(fmaxf(red[t][0], red[t][1]), fmaxf(red[t][2], red[t][3]));
        rowmax[t] = fmaxf(m, pos_adj_s[t]);
    }
    __syncthreads();
    #pragma unroll
    for (int r = 0; r < ROWS; ++r) {
        const float mr = rowmax[r];
        float s = 0.0f;
        #pragma unroll
        for (int k = 0; k < 8; ++k) s += expf(acc[r][k] - mr);
        s += __shfl_xor(s, 1);
        s += __shfl_xor(s, 2);
        s += __shfl_xor(s, 4);
        s += __shfl_xor(s, 8);
        s += __shfl_xor(s, 16);
        s += __shfl_xor(s, 32);
        if (lane == 0) red[r][wave] = s;
    }
    __syncthreads();

    float pl = 0.0f, pw = 0.0f;
    if (t < ROWS) {
        float s = red[t][0] + red[t][1] + red[t][2] + red[t][3];
        s += expf(pos_adj_s[t] - rowmax[t]);
        const float lse = rowmax[t] + logf(s);
        const float per = lse - pos_adj_s[t];
        pw = (yf_s[t] != 0) ? 1.0f : 0.0f;
        pl = per * pw;
    }
    if (wave == 0) {
        pl += __shfl_xor(pl, 1); pw += __shfl_xor(pw, 1);
        pl += __shfl_xor(pl, 2); pw += __shfl_xor(pw, 2);
        pl += __shfl_xor(pl, 4); pw += __shfl_xor(pw, 4);
        if (lane == 0) partials[blockIdx.x] = make_float2(pl, pw);
    }
}

// ---------------- finalize: deterministic reduction ----------------
__global__ __launch_bounds__(TPB) void sspe_finalize(
    const float2* __restrict__ partials, int n, float* __restrict__ out)
{
    __shared__ float ssum[TPB];
    __shared__ float scnt[TPB];
    const int t = threadIdx.x;
    float s = 0.0f, c = 0.0f;
    for (int i = t; i < n; i += TPB) {
        const float2 p = partials[i];
        s += p.x; c += p.y;
    }
    ssum[t] = s; scnt[t] = c;
    __syncthreads();
    for (int k = TPB / 2; k > 0; k >>= 1) {
        if (t < k) { ssum[t] += ssum[t + k]; scnt[t] += scnt[t + k]; }
        __syncthreads();
    }
    if (t == 0) out[0] = ssum[0] / fmaxf(scnt[0], 1.0f);
}

extern "C" void kernel_launch(void* const* d_in, const int* in_sizes, int n_in,
                              void* d_out, int out_size, void* d_ws, size_t ws_size,
                              hipStream_t stream) {
    const float* hidden = (const float*)d_in[0];
    const int*   yv     = (const int*)d_in[1];
    const float* embed  = (const float*)d_in[2];
    const float* sprobs = (const float*)d_in[3];
    const int*   sidx   = (const int*)d_in[4];
    const float* ltemp  = (const float*)d_in[5];
    float* out = (float*)d_out;

    const int nrows = in_sizes[1];          // B*S = 65536
    const int nblocks = nrows / ROWS;       // 8192

    char* w = (char*)d_ws;
    float*  en_t    = (float*)w;                                         // 128*2048*4 = 1 MB
    float*  ln_samp = (float*)(w + (size_t)D * NNEG * 4);                // 8 KB
    float2* partials = (float2*)(w + (size_t)D * NNEG * 4 + NNEG * 4);   // 64 KB

    sspe_prep<<<NNEG / 4, TPB, 0, stream>>>(embed, sprobs, sidx, en_t, ln_samp);
    sspe_main<<<nblocks, TPB, 0, stream>>>(hidden, yv, embed, sprobs, sidx, ltemp,
                                           en_t, ln_samp, partials);
    sspe_finalize<<<1, TPB, 0, stream>>>(partials, nblocks, out);
}

// Round 2
// 124.974 us; speedup vs baseline: 3.9754x; 3.9754x over previous
//
#include <hip/hip_runtime.h>
#include <math.h>

#define TPB 256
#define NNEG 2048
#define D 128
#define L2E 1.44269504088896340736f

typedef __attribute__((ext_vector_type(8))) short bf16x8;
typedef __attribute__((ext_vector_type(4))) float f32x4;

#define MFMA16 __builtin_amdgcn_mfma_f32_16x16x32_bf16

static __device__ __forceinline__ unsigned int f2bf(float f) {
    unsigned int u = __float_as_uint(f);
    return (u + 0x7FFFu + ((u >> 16) & 1u)) >> 16;
}

// ---------------- prep: normalize negatives -> bf16 [NNEG][D], + log(samp_p) ----------------
__global__ __launch_bounds__(TPB) void sspe_prep(
    const float* __restrict__ embed,
    const float* __restrict__ sprobs,
    const int* __restrict__ sidx,
    unsigned int* __restrict__ en_bf,   // [NNEG][D] bf16, viewed as uint pairs
    float* __restrict__ ln_samp)        // [NNEG]
{
    const int t = threadIdx.x;
    const int wave = t >> 6;
    const int lane = t & 63;
    const int j = blockIdx.x * 4 + wave;
    const int idx = sidx[j];

    float2 v = reinterpret_cast<const float2*>(embed)[(size_t)idx * 64 + lane];
    float ss = v.x * v.x + v.y * v.y;
    ss += __shfl_xor(ss, 1);
    ss += __shfl_xor(ss, 2);
    ss += __shfl_xor(ss, 4);
    ss += __shfl_xor(ss, 8);
    ss += __shfl_xor(ss, 16);
    ss += __shfl_xor(ss, 32);
    const float rinv = 1.0f / fmaxf(sqrtf(ss), 1e-12f);
    en_bf[(size_t)j * 64 + lane] = f2bf(v.x * rinv) | (f2bf(v.y * rinv) << 16);
    if (lane == 0) ln_samp[j] = logf(sprobs[idx] + 1e-10f);
}

// ---------------- main: fused normalize + pos + MFMA GEMM + masked sum-exp ----------------
__global__ __launch_bounds__(TPB, 2) void sspe_main(
    const float* __restrict__ hidden,
    const int* __restrict__ y,
    const float* __restrict__ embed,
    const float* __restrict__ sprobs,
    const int* __restrict__ sidx,
    const float* __restrict__ ltemp,
    const unsigned int* __restrict__ en_bf,
    const float* __restrict__ ln_samp,
    float2* __restrict__ partials)
{
    const int t = threadIdx.x;
    const int wave = t >> 6;
    const int lane = t & 63;
    const int rb = blockIdx.x * 64;          // 64 rows per block

    __shared__ __align__(16) unsigned char hs[64 * 256];  // 64 rows x 128 bf16, XOR-swizzled
    __shared__ float pos_s[64];
    __shared__ float sred[4][64];

    const float temp = __builtin_amdgcn_exp2f(fminf(ltemp[0], 4.6f) * L2E);
    const float t2 = temp * L2E;

    // ---- Prologue: per wave, normalize 16 rows -> bf16 LDS (swizzled) + pos logits ----
    for (int i = 0; i < 16; ++i) {
        const int lr = wave * 16 + i;
        const int row = rb + lr;
        const float2 h2 = reinterpret_cast<const float2*>(hidden)[(size_t)row * 64 + lane];
        const int yi = y[row];
        const float2 e2 = reinterpret_cast<const float2*>(embed)[(size_t)yi * 64 + lane];
        float ss = h2.x * h2.x + h2.y * h2.y;
        float es = e2.x * e2.x + e2.y * e2.y;
        float dt = h2.x * e2.x + h2.y * e2.y;
        #pragma unroll
        for (int m = 1; m <= 32; m <<= 1) {
            ss += __shfl_xor(ss, m);
            es += __shfl_xor(es, m);
            dt += __shfl_xor(dt, m);
        }
        const float rinv = 1.0f / fmaxf(sqrtf(ss), 1e-12f);
        const unsigned int u = f2bf(h2.x * rinv) | (f2bf(h2.y * rinv) << 16);
        const int rx = (lr & 7) << 4;
        *reinterpret_cast<unsigned int*>(hs + lr * 256 + ((lane * 4) ^ rx)) = u;
        if (lane == 0) {
            const float pl = dt * rinv * (1.0f / fmaxf(sqrtf(es), 1e-12f)) * temp;
            pos_s[lr] = pl - logf(sprobs[yi] + 1e-10f);
        }
    }
    __syncthreads();

    // ---- Load A fragments (4 row-tiles x 4 k-steps) from swizzled LDS ----
    bf16x8 A[4][4];
    #pragma unroll
    for (int rt = 0; rt < 4; ++rt) {
        const int row = rt * 16 + (lane & 15);
        const int rx = (row & 7) << 4;
        const unsigned char* rp = hs + row * 256;
        #pragma unroll
        for (int ks = 0; ks < 4; ++ks) {
            const int col = ((ks * 64) + ((lane >> 4) << 4)) ^ rx;
            A[rt][ks] = *reinterpret_cast<const bf16x8*>(rp + col);
        }
    }

    // ---- Per-row constants: m2 = max(pos_adj, temp)*L2E, labels ----
    float m2[4][4];
    int yv[4][4];
    float l[4][4];
    #pragma unroll
    for (int rt = 0; rt < 4; ++rt)
        #pragma unroll
        for (int j = 0; j < 4; ++j) {
            const int lr = rt * 16 + ((lane >> 4) << 2) + j;
            m2[rt][j] = fmaxf(pos_s[lr], temp) * L2E;
            yv[rt][j] = y[rb + lr];
            l[rt][j] = 0.0f;
        }

    // ---- Main loop: this wave's 512-neg range, 16 negs per iteration ----
    const int nw = wave * 512;
    const unsigned char* pB = reinterpret_cast<const unsigned char*>(en_bf)
                            + (size_t)(nw + (lane & 15)) * 256 + ((lane >> 4) << 4);
    const float* pL = ln_samp + nw + (lane & 15);
    const int* pI = sidx + nw + (lane & 15);

    for (int nb = 0; nb < 32; ++nb) {
        const bf16x8 b0 = *reinterpret_cast<const bf16x8*>(pB);
        const bf16x8 b1 = *reinterpret_cast<const bf16x8*>(pB + 64);
        const bf16x8 b2 = *reinterpret_cast<const bf16x8*>(pB + 128);
        const bf16x8 b3 = *reinterpret_cast<const bf16x8*>(pB + 192);
        const float lnk = *pL;
        const int ci = *pI;

        f32x4 c0 = {0.f, 0.f, 0.f, 0.f};
        f32x4 c1 = c0, c2 = c0, c3 = c0;
        c0 = MFMA16(A[0][0], b0, c0, 0, 0, 0);
        c1 = MFMA16(A[1][0], b0, c1, 0, 0, 0);
        c2 = MFMA16(A[2][0], b0, c2, 0, 0, 0);
        c3 = MFMA16(A[3][0], b0, c3, 0, 0, 0);
        c0 = MFMA16(A[0][1], b1, c0, 0, 0, 0);
        c1 = MFMA16(A[1][1], b1, c1, 0, 0, 0);
        c2 = MFMA16(A[2][1], b1, c2, 0, 0, 0);
        c3 = MFMA16(A[3][1], b1, c3, 0, 0, 0);
        c0 = MFMA16(A[0][2], b2, c0, 0, 0, 0);
        c1 = MFMA16(A[1][2], b2, c1, 0, 0, 0);
        c2 = MFMA16(A[2][2], b2, c2, 0, 0, 0);
        c3 = MFMA16(A[3][2], b2, c3, 0, 0, 0);
        c0 = MFMA16(A[0][3], b3, c0, 0, 0, 0);
        c1 = MFMA16(A[1][3], b3, c1, 0, 0, 0);
        c2 = MFMA16(A[2][3], b3, c2, 0, 0, 0);
        c3 = MFMA16(A[3][3], b3, c3, 0, 0, 0);

        const float nl2 = -lnk * L2E;
        #pragma unroll
        for (int j = 0; j < 4; ++j) {
            float a0 = fmaf(c0[j], t2, nl2) - m2[0][j];
            float a1 = fmaf(c1[j], t2, nl2) - m2[1][j];
            float a2 = fmaf(c2[j], t2, nl2) - m2[2][j];
            float a3 = fmaf(c3[j], t2, nl2) - m2[3][j];
            if (ci == yv[0][j]) a0 = -INFINITY;
            if (ci == yv[1][j]) a1 = -INFINITY;
            if (ci == yv[2][j]) a2 = -INFINITY;
            if (ci == yv[3][j]) a3 = -INFINITY;
            l[0][j] += __builtin_amdgcn_exp2f(a0);
            l[1][j] += __builtin_amdgcn_exp2f(a1);
            l[2][j] += __builtin_amdgcn_exp2f(a2);
            l[3][j] += __builtin_amdgcn_exp2f(a3);
        }
        pB += 4096;
        pL += 16;
        pI += 16;
    }

    // ---- Reduce l over the 16 column-classes (lanes sharing lane>>4 group) ----
    #pragma unroll
    for (int rt = 0; rt < 4; ++rt)
        #pragma unroll
        for (int j = 0; j < 4; ++j) {
            float v = l[rt][j];
            v += __shfl_xor(v, 1);
            v += __shfl_xor(v, 2);
            v += __shfl_xor(v, 4);
            v += __shfl_xor(v, 8);
            l[rt][j] = v;
        }
    if ((lane & 15) == 0) {
        #pragma unroll
        for (int rt = 0; rt < 4; ++rt)
            #pragma unroll
            for (int j = 0; j < 4; ++j)
                sred[wave][rt * 16 + ((lane >> 4) << 2) + j] = l[rt][j];
    }
    __syncthreads();

    // ---- Per-row loss + block reduce (wave 0) ----
    if (t < 64) {
        const float s = sred[0][t] + sred[1][t] + sred[2][t] + sred[3][t];
        const float pa = pos_s[t];
        const float m = fmaxf(pa, temp);
        const float stot = s + __builtin_amdgcn_exp2f((pa - m) * L2E);
        float per = m + logf(stot) - pa;
        float w = (y[rb + t] != 0) ? 1.0f : 0.0f;
        per *= w;
        #pragma unroll
        for (int msk = 1; msk < 64; msk <<= 1) {
            per += __shfl_xor(per, msk);
            w += __shfl_xor(w, msk);
        }
        if (t == 0) partials[blockIdx.x] = make_float2(per, w);
    }
}

// ---------------- finalize: deterministic reduction ----------------
__global__ __launch_bounds__(TPB) void sspe_finalize(
    const float2* __restrict__ partials, int n, float* __restrict__ out)
{
    __shared__ float ssum[TPB];
    __shared__ float scnt[TPB];
    const int t = threadIdx.x;
    float s = 0.0f, c = 0.0f;
    for (int i = t; i < n; i += TPB) {
        const float2 p = partials[i];
        s += p.x; c += p.y;
    }
    ssum[t] = s; scnt[t] = c;
    __syncthreads();
    for (int k = TPB / 2; k > 0; k >>= 1) {
        if (t < k) { ssum[t] += ssum[t + k]; scnt[t] += scnt[t + k]; }
        __syncthreads();
    }
    if (t == 0) out[0] = ssum[0] / fmaxf(scnt[0], 1.0f);
}

extern "C" void kernel_launch(void* const* d_in, const int* in_sizes, int n_in,
                              void* d_out, int out_size, void* d_ws, size_t ws_size,
                              hipStream_t stream) {
    const float* hidden = (const float*)d_in[0];
    const int*   yv     = (const int*)d_in[1];
    const float* embed  = (const float*)d_in[2];
    const float* sprobs = (const float*)d_in[3];
    const int*   sidx   = (const int*)d_in[4];
    const float* ltemp  = (const float*)d_in[5];
    float* out = (float*)d_out;

    const int nrows = in_sizes[1];             // 65536
    const int nblocks = nrows / 64;            // 1024

    char* w = (char*)d_ws;
    unsigned int* en_bf  = (unsigned int*)w;                            // 512 KB
    float*  ln_samp      = (float*)(w + (size_t)NNEG * D * 2);          // 8 KB
    float2* partials     = (float2*)(w + (size_t)NNEG * D * 2 + NNEG * 4);

    sspe_prep<<<NNEG / 4, TPB, 0, stream>>>(embed, sprobs, sidx, en_bf, ln_samp);
    sspe_main<<<nblocks, TPB, 0, stream>>>(hidden, yv, embed, sprobs, sidx, ltemp,
                                           en_bf, ln_samp, partials);
    sspe_finalize<<<1, TPB, 0, stream>>>(partials, nblocks, out);
}

// Round 3
// 98.488 us; speedup vs baseline: 5.0445x; 1.2689x over previous
//
#include <hip/hip_runtime.h>
#include <math.h>

#define TPB 256
#define NNEG 2048
#define D 128
#define L2E 1.44269504088896340736f

typedef __attribute__((ext_vector_type(8))) short bf16x8;
typedef __attribute__((ext_vector_type(4))) float f32x4;

#define MFMA16 __builtin_amdgcn_mfma_f32_16x16x32_bf16

static __device__ __forceinline__ unsigned int f2bf(float f) {
    unsigned int u = __float_as_uint(f);
    return (u + 0x7FFFu + ((u >> 16) & 1u)) >> 16;
}

// ---------------- prep: normalize negatives -> bf16 [NNEG][D], + log(samp_p) ----------------
__global__ __launch_bounds__(TPB) void sspe_prep(
    const float* __restrict__ embed,
    const float* __restrict__ sprobs,
    const int* __restrict__ sidx,
    unsigned int* __restrict__ en_bf,
    float* __restrict__ ln_samp)
{
    const int t = threadIdx.x;
    const int wave = t >> 6;
    const int lane = t & 63;
    const int j = blockIdx.x * 4 + wave;
    const int idx = sidx[j];

    float2 v = reinterpret_cast<const float2*>(embed)[(size_t)idx * 64 + lane];
    float ss = v.x * v.x + v.y * v.y;
    ss += __shfl_xor(ss, 1);
    ss += __shfl_xor(ss, 2);
    ss += __shfl_xor(ss, 4);
    ss += __shfl_xor(ss, 8);
    ss += __shfl_xor(ss, 16);
    ss += __shfl_xor(ss, 32);
    const float rinv = 1.0f / fmaxf(sqrtf(ss), 1e-12f);
    en_bf[(size_t)j * 64 + lane] = f2bf(v.x * rinv) | (f2bf(v.y * rinv) << 16);
    if (lane == 0) ln_samp[j] = logf(sprobs[idx] + 1e-10f);
}

// ---------------- compute one 16-neg tile: 16 MFMA + epilogue ----------------
static __device__ __forceinline__ void compute_tile(
    const bf16x8 (&A)[4][4], const bf16x8 (&B)[4], const float lk, const int ci,
    const int (&yv)[4][4], float (&l)[4][4], const float t2, const float M2)
{
    f32x4 c[4];
    #pragma unroll
    for (int rt = 0; rt < 4; ++rt) c[rt] = (f32x4){0.f, 0.f, 0.f, 0.f};
    #pragma unroll
    for (int ks = 0; ks < 4; ++ks)
        #pragma unroll
        for (int rt = 0; rt < 4; ++rt)
            c[rt] = MFMA16(A[rt][ks], B[ks], c[rt], 0, 0, 0);
    const float nl2 = fmaf(lk, -L2E, -M2);
    #pragma unroll
    for (int rt = 0; rt < 4; ++rt)
        #pragma unroll
        for (int j = 0; j < 4; ++j) {
            const float a = fmaf(c[rt][j], t2, nl2);
            const float e = __builtin_amdgcn_exp2f(a);
            l[rt][j] += (ci == yv[rt][j]) ? 0.0f : e;
        }
}

#define LOADB(B, LK, CI, it) do {                                  \
    const unsigned char* q_ = pB + (size_t)(it) * 4096;            \
    B[0] = *reinterpret_cast<const bf16x8*>(q_);                   \
    B[1] = *reinterpret_cast<const bf16x8*>(q_ + 64);              \
    B[2] = *reinterpret_cast<const bf16x8*>(q_ + 128);             \
    B[3] = *reinterpret_cast<const bf16x8*>(q_ + 192);             \
    LK = pL[(it) * 16];                                            \
    CI = pI[(it) * 16];                                            \
} while (0)

// ---------------- main: fused normalize + pos + MFMA GEMM + masked sum-exp ----------------
__global__ __launch_bounds__(TPB, 2) void sspe_main(
    const float* __restrict__ hidden,
    const int* __restrict__ y,
    const float* __restrict__ embed,
    const float* __restrict__ sprobs,
    const int* __restrict__ sidx,
    const float* __restrict__ ltemp,
    const unsigned int* __restrict__ en_bf,
    const float* __restrict__ ln_samp,
    float2* __restrict__ partials)
{
    const int t = threadIdx.x;
    const int wave = t >> 6;
    const int lane = t & 63;
    const int rb = blockIdx.x * 64;

    __shared__ __align__(16) unsigned char hs[64 * 256];
    __shared__ float pos_s[64];
    __shared__ int   ys[64];
    __shared__ float sred[4][64];

    const float temp = __builtin_amdgcn_exp2f(fminf(ltemp[0], 4.6f) * L2E);
    const float t2 = temp * L2E;
    const float Mln = temp + 14.0f;         // uniform safe max (|cos|<=1, -log p <= 13.8)
    const float M2 = Mln * L2E;

    if (t < 64) ys[t] = y[rb + t];
    __syncthreads();

    // ---- Prologue: 4 rows per step, gathers batched for MLP ----
    #pragma unroll 1
    for (int i = 0; i < 16; i += 4) {
        float2 h2[4], e2[4];
        int yi[4];
        #pragma unroll
        for (int u = 0; u < 4; ++u) {
            const int lr = wave * 16 + i + u;
            h2[u] = reinterpret_cast<const float2*>(hidden)[(size_t)(rb + lr) * 64 + lane];
            yi[u] = ys[lr];
        }
        #pragma unroll
        for (int u = 0; u < 4; ++u)
            e2[u] = reinterpret_cast<const float2*>(embed)[(size_t)yi[u] * 64 + lane];
        float ss[4], es[4], dt[4];
        #pragma unroll
        for (int u = 0; u < 4; ++u) {
            ss[u] = h2[u].x * h2[u].x + h2[u].y * h2[u].y;
            es[u] = e2[u].x * e2[u].x + e2[u].y * e2[u].y;
            dt[u] = h2[u].x * e2[u].x + h2[u].y * e2[u].y;
        }
        #pragma unroll
        for (int m = 1; m <= 32; m <<= 1)
            #pragma unroll
            for (int u = 0; u < 4; ++u) {
                ss[u] += __shfl_xor(ss[u], m);
                es[u] += __shfl_xor(es[u], m);
                dt[u] += __shfl_xor(dt[u], m);
            }
        #pragma unroll
        for (int u = 0; u < 4; ++u) {
            const int lr = wave * 16 + i + u;
            const float rinv = 1.0f / fmaxf(sqrtf(ss[u]), 1e-12f);
            const unsigned int uu = f2bf(h2[u].x * rinv) | (f2bf(h2[u].y * rinv) << 16);
            const int rx = (lr & 7) << 4;
            *reinterpret_cast<unsigned int*>(hs + lr * 256 + ((lane * 4) ^ rx)) = uu;
            if (lane == 0)
                pos_s[lr] = dt[u] * rinv * (1.0f / fmaxf(sqrtf(es[u]), 1e-12f)) * temp
                            - logf(sprobs[yi[u]] + 1e-10f);
        }
    }
    __syncthreads();

    // ---- A fragments from swizzled LDS ----
    bf16x8 A[4][4];
    #pragma unroll
    for (int rt = 0; rt < 4; ++rt) {
        const int row = rt * 16 + (lane & 15);
        const int rx = (row & 7) << 4;
        const unsigned char* rp = hs + row * 256;
        #pragma unroll
        for (int ks = 0; ks < 4; ++ks) {
            const int col = ((ks * 64) + ((lane >> 4) << 4)) ^ rx;
            A[rt][ks] = *reinterpret_cast<const bf16x8*>(rp + col);
        }
    }

    int yv[4][4];
    float l[4][4];
    #pragma unroll
    for (int rt = 0; rt < 4; ++rt)
        #pragma unroll
        for (int j = 0; j < 4; ++j) {
            yv[rt][j] = ys[rt * 16 + ((lane >> 4) << 2) + j];
            l[rt][j] = 0.0f;
        }

    // ---- Main loop: software-pipelined, 2 tiles per iteration ----
    const int nw = wave * 512;
    const unsigned char* pB = reinterpret_cast<const unsigned char*>(en_bf)
                            + (size_t)(nw + (lane & 15)) * 256 + ((lane >> 4) << 4);
    const float* pL = ln_samp + nw + (lane & 15);
    const int* pI = sidx + nw + (lane & 15);

    bf16x8 B0[4], B1[4];
    float lk0, lk1;
    int ci0, ci1;

    LOADB(B0, lk0, ci0, 0);
    #pragma unroll 1
    for (int nb = 0; nb < 30; nb += 2) {
        LOADB(B1, lk1, ci1, nb + 1);
        compute_tile(A, B0, lk0, ci0, yv, l, t2, M2);
        LOADB(B0, lk0, ci0, nb + 2);
        compute_tile(A, B1, lk1, ci1, yv, l, t2, M2);
    }
    LOADB(B1, lk1, ci1, 31);
    compute_tile(A, B0, lk0, ci0, yv, l, t2, M2);
    compute_tile(A, B1, lk1, ci1, yv, l, t2, M2);

    // ---- Reduce l across the 4 column-groups ----
    #pragma unroll
    for (int rt = 0; rt < 4; ++rt)
        #pragma unroll
        for (int j = 0; j < 4; ++j) {
            float v = l[rt][j];
            v += __shfl_xor(v, 1);
            v += __shfl_xor(v, 2);
            v += __shfl_xor(v, 4);
            v += __shfl_xor(v, 8);
            l[rt][j] = v;
        }
    if ((lane & 15) == 0) {
        #pragma unroll
        for (int rt = 0; rt < 4; ++rt)
            #pragma unroll
            for (int j = 0; j < 4; ++j)
                sred[wave][rt * 16 + ((lane >> 4) << 2) + j] = l[rt][j];
    }
    __syncthreads();

    // ---- Per-row loss + block reduce ----
    if (t < 64) {
        const float s = sred[0][t] + sred[1][t] + sred[2][t] + sred[3][t];
        const float pa = pos_s[t];
        const float stot = s + __builtin_amdgcn_exp2f(fmaf(pa, L2E, -M2));
        float per = Mln + logf(stot) - pa;
        float w = (ys[t] != 0) ? 1.0f : 0.0f;
        per *= w;
        #pragma unroll
        for (int msk = 1; msk < 64; msk <<= 1) {
            per += __shfl_xor(per, msk);
            w += __shfl_xor(w, msk);
        }
        if (t == 0) partials[blockIdx.x] = make_float2(per, w);
    }
}

// ---------------- finalize: deterministic reduction ----------------
__global__ __launch_bounds__(TPB) void sspe_finalize(
    const float2* __restrict__ partials, int n, float* __restrict__ out)
{
    __shared__ float ssum[TPB];
    __shared__ float scnt[TPB];
    const int t = threadIdx.x;
    float s = 0.0f, c = 0.0f;
    for (int i = t; i < n; i += TPB) {
        const float2 p = partials[i];
        s += p.x; c += p.y;
    }
    ssum[t] = s; scnt[t] = c;
    __syncthreads();
    for (int k = TPB / 2; k > 0; k >>= 1) {
        if (t < k) { ssum[t] += ssum[t + k]; scnt[t] += scnt[t + k]; }
        __syncthreads();
    }
    if (t == 0) out[0] = ssum[0] / fmaxf(scnt[0], 1.0f);
}

extern "C" void kernel_launch(void* const* d_in, const int* in_sizes, int n_in,
                              void* d_out, int out_size, void* d_ws, size_t ws_size,
                              hipStream_t stream) {
    const float* hidden = (const float*)d_in[0];
    const int*   yv     = (const int*)d_in[1];
    const float* embed  = (const float*)d_in[2];
    const float* sprobs = (const float*)d_in[3];
    const int*   sidx   = (const int*)d_in[4];
    const float* ltemp  = (const float*)d_in[5];
    float* out = (float*)d_out;

    const int nrows = in_sizes[1];
    const int nblocks = nrows / 64;

    char* w = (char*)d_ws;
    unsigned int* en_bf  = (unsigned int*)w;
    float*  ln_samp      = (float*)(w + (size_t)NNEG * D * 2);
    float2* partials     = (float2*)(w + (size_t)NNEG * D * 2 + NNEG * 4);

    sspe_prep<<<NNEG / 4, TPB, 0, stream>>>(embed, sprobs, sidx, en_bf, ln_samp);
    sspe_main<<<nblocks, TPB, 0, stream>>>(hidden, yv, embed, sprobs, sidx, ltemp,
                                           en_bf, ln_samp, partials);
    sspe_finalize<<<1, TPB, 0, stream>>>(partials, nblocks, out);
}